// Round 1
// baseline (147.250 us; speedup 1.0000x reference)
//
#include <hip/hip_runtime.h>
#include <hip/hip_bf16.h>

#define SEQ 394
#define EMB 300
#define DEPTH 256

typedef __attribute__((ext_vector_type(8))) short short8;
typedef __attribute__((ext_vector_type(4))) float f32x4;

__device__ __forceinline__ unsigned short f2b(float f) {
    unsigned u = __float_as_uint(f);
    u += 0x7FFFu + ((u >> 16) & 1u);   // RNE to bf16
    return (unsigned short)(u >> 16);
}

__device__ __forceinline__ void load_chunk(const float* __restrict__ Wg,
                                           const float* __restrict__ xb,
                                           int K, int dbase, int i0, int k0, int tid,
                                           float4 wv[4], float4 xv[4])
{
#pragma unroll
    for (int i = 0; i < 4; ++i) {
        int fi  = tid + (i << 8);
        int row = fi >> 3;            // 0..127
        int c4  = (fi & 7) << 2;      // 0,4,...,28
        int col = k0 + c4;
        if (col < K)
            wv[i] = *(const float4*)(Wg + (long)(dbase + row) * K + col);
        else
            wv[i] = make_float4(0.f, 0.f, 0.f, 0.f);   // zero-pad W beyond K
        int off = (i0 + row) * EMB + col;              // flat x offset (im2col-free)
        int lim = SEQ * EMB - 4;
        if (off > lim) off = lim;                      // clamp: only invalid windows affected
        xv[i] = *(const float4*)(xb + off);
    }
}

__device__ __forceinline__ void write_chunk(unsigned short (*Wb)[40],
                                            unsigned short (*Xb)[40],
                                            int tid, const float4 wv[4], const float4 xv[4])
{
#pragma unroll
    for (int i = 0; i < 4; ++i) {
        int fi  = tid + (i << 8);
        int row = fi >> 3;
        int c4  = (fi & 7) << 2;
        *(ushort4*)&Wb[row][c4] = make_ushort4(f2b(wv[i].x), f2b(wv[i].y), f2b(wv[i].z), f2b(wv[i].w));
        *(ushort4*)&Xb[row][c4] = make_ushort4(f2b(xv[i].x), f2b(xv[i].y), f2b(xv[i].z), f2b(xv[i].w));
    }
}

__global__ __launch_bounds__(256, 2)
void convmax_kernel(const float* __restrict__ x,
                    const float* __restrict__ W1, const float* __restrict__ W2,
                    const float* __restrict__ W3,
                    const float* __restrict__ b1, const float* __restrict__ b2,
                    const float* __restrict__ b3,
                    float* __restrict__ out)
{
    const int br = blockIdx.z;
    const int K  = (br == 0) ? 900 : (br == 1) ? 1200 : 1500;
    const int Nw = SEQ - 3 - br;                 // valid windows: 391/390/389
    const float* Wg = (br == 0) ? W1 : (br == 1) ? W2 : W3;
    const float* bg = (br == 0) ? b1 : (br == 1) ? b2 : b3;
    const int b  = blockIdx.x;
    const int mt = blockIdx.y >> 2;              // 0..1
    const int nt = blockIdx.y & 3;               // 0..3
    const int dbase = mt * 128;
    const int i0    = nt * 128;
    const float* xb = x + b * (SEQ * EMB);
    const int nch = (K + 31) >> 5;               // K-chunks of 32

    __shared__ unsigned short Wl[2][128][40];    // +8 pad: conflict-free b128 reads
    __shared__ unsigned short Xl[2][128][40];

    const int tid  = threadIdx.x;
    const int lane = tid & 63;
    const int wid  = tid >> 6;
    const int wr = wid >> 1, wc = wid & 1;       // wave tile (64 filt x 64 win)
    const int lr = lane & 15, lg = lane >> 4;

    f32x4 acc[4][4];
#pragma unroll
    for (int i = 0; i < 4; ++i)
#pragma unroll
        for (int j = 0; j < 4; ++j)
            acc[i][j] = (f32x4)0.0f;

    // prologue: stage chunk 0 into buf 0
    {
        float4 wv[4], xv[4];
        load_chunk(Wg, xb, K, dbase, i0, 0, tid, wv, xv);
        write_chunk(Wl[0], Xl[0], tid, wv, xv);
    }
    __syncthreads();

    for (int c = 0; c < nch; ++c) {
        const int cur = c & 1;
        float4 wv[4], xv[4];
        const bool pf = (c + 1 < nch);
        if (pf) load_chunk(Wg, xb, K, dbase, i0, (c + 1) << 5, tid, wv, xv);

        // compute on current buffer: 4x4 frags, K-step 32
        short8 af[4], bfr[4];
#pragma unroll
        for (int mi = 0; mi < 4; ++mi)
            af[mi] = *(const short8*)&Wl[cur][wr * 64 + mi * 16 + lr][lg * 8];
#pragma unroll
        for (int ni = 0; ni < 4; ++ni)
            bfr[ni] = *(const short8*)&Xl[cur][wc * 64 + ni * 16 + lr][lg * 8];
#pragma unroll
        for (int mi = 0; mi < 4; ++mi)
#pragma unroll
            for (int ni = 0; ni < 4; ++ni)
                acc[mi][ni] = __builtin_amdgcn_mfma_f32_16x16x32_bf16(af[mi], bfr[ni], acc[mi][ni], 0, 0, 0);

        if (pf) write_chunk(Wl[cur ^ 1], Xl[cur ^ 1], tid, wv, xv);
        __syncthreads();
    }

    // epilogue: bias + relu + mask invalid windows + max-reduce + atomicMax
    const int ob = b * 768 + br * 256;
#pragma unroll
    for (int mi = 0; mi < 4; ++mi) {
#pragma unroll
        for (int r = 0; r < 4; ++r) {
            const int d = dbase + wr * 64 + mi * 16 + lg * 4 + r;  // C/D: row=(lane>>4)*4+reg
            const float bv = bg[d];
            float m = 0.f;
#pragma unroll
            for (int ni = 0; ni < 4; ++ni) {
                int win = i0 + wc * 64 + ni * 16 + lr;             // C/D: col=lane&15
                float v = acc[mi][ni][r] + bv;
                v = fmaxf(v, 0.f);
                if (win >= Nw) v = 0.f;                            // mask; identity of max (>=0)
                m = fmaxf(m, v);
            }
#pragma unroll
            for (int off = 1; off < 16; off <<= 1)
                m = fmaxf(m, __shfl_xor(m, off));
            if (lr == 0)
                atomicMax((int*)(out + ob + d), __float_as_int(m)); // vals >= 0: int order == float order
        }
    }
}

extern "C" void kernel_launch(void* const* d_in, const int* in_sizes, int n_in,
                              void* d_out, int out_size, void* d_ws, size_t ws_size,
                              hipStream_t stream) {
    const float* x  = (const float*)d_in[0];
    const float* W1 = (const float*)d_in[1];
    const float* W2 = (const float*)d_in[2];
    const float* W3 = (const float*)d_in[3];
    const float* b1 = (const float*)d_in[4];
    const float* b2 = (const float*)d_in[5];
    const float* b3 = (const float*)d_in[6];
    float* out = (float*)d_out;

    hipMemsetAsync(d_out, 0, (size_t)out_size * sizeof(float), stream);

    dim3 grid(64, 8, 3);   // batch x (mtile*4+ntile) x branch
    dim3 block(256);
    convmax_kernel<<<grid, block, 0, stream>>>(x, W1, W2, W3, b1, b2, b3, out);
}

// Round 2
// 134.992 us; speedup vs baseline: 1.0908x; 1.0908x over previous
//
#include <hip/hip_runtime.h>
#include <hip/hip_bf16.h>

#define SEQ 394
#define EMB 300
#define DEPTH 256

typedef __attribute__((ext_vector_type(8))) short short8;
typedef __attribute__((ext_vector_type(4))) float f32x4;

__device__ __forceinline__ unsigned short f2b(float f) {
    unsigned u = __float_as_uint(f);
    u += 0x7FFFu + ((u >> 16) & 1u);   // RNE to bf16
    return (unsigned short)(u >> 16);
}

__device__ __forceinline__ void gload_lds16(const void* g, void* l) {
    __builtin_amdgcn_global_load_lds(
        (const __attribute__((address_space(1))) void*)g,
        (__attribute__((address_space(3))) void*)l, 16, 0, 0);
}

// ---------------- pack kernels ----------------

// x fp32 -> bf16, two copies: xp (plain) and xsh (shifted by 4 elements so
// odd im2col rows get 16B-aligned 16B loads)
__global__ __launch_bounds__(256)
void pack_x_kernel(const float* __restrict__ x,
                   unsigned short* __restrict__ xp,
                   unsigned short* __restrict__ xsh)
{
    const long TOT = (long)64 * SEQ * EMB;           // 7,564,800
    long i4 = ((long)blockIdx.x * 256 + threadIdx.x) * 4;
    if (i4 >= TOT) return;
    float4 v = *(const float4*)(x + i4);
    ushort4 u = make_ushort4(f2b(v.x), f2b(v.y), f2b(v.z), f2b(v.w));
    *(ushort4*)(xp + i4) = u;
    if (i4 >= 4) *(ushort4*)(xsh + i4 - 4) = u;      // xsh[e-4] = x[e]
}

// W fp32 -> bf16, rows padded (zero) to Kp multiple of 32
__global__ __launch_bounds__(256)
void pack_w_kernel(const float* __restrict__ W1, const float* __restrict__ W2,
                   const float* __restrict__ W3, unsigned short* __restrict__ wp)
{
    const int br = blockIdx.z;
    const int K  = 900 + br * 300;
    const int Kp = (br == 0) ? 928 : (br == 1) ? 1216 : 1504;
    const float* Wg = (br == 0) ? W1 : (br == 1) ? W2 : W3;
    unsigned short* dst = wp + ((br == 0) ? 0 : (br == 1) ? 256 * 928 : 256 * (928 + 1216));
    int idx = blockIdx.x * 256 + threadIdx.x;
    int tot = 256 * (Kp >> 2);
    if (idx >= tot) return;
    int kq = Kp >> 2;
    int d  = idx / kq;
    int k4 = (idx - d * kq) * 4;
    ushort4 u;
    if (k4 < K) {
        float4 v = *(const float4*)(Wg + (long)d * K + k4);
        u = make_ushort4(f2b(v.x), f2b(v.y), f2b(v.z), f2b(v.w));
    } else {
        u = make_ushort4(0, 0, 0, 0);
    }
    *(ushort4*)(dst + (long)d * Kp + k4) = u;
}

// ---------------- main GEMM (m97 structure: global_load_lds w16) ----------------
// N is batch-merged: n = b*Nw + i. Tiles: 128 filters x 128 windows, BK=32.

__global__ __launch_bounds__(256)
void gemm_kernel(const unsigned short* __restrict__ xp,
                 const unsigned short* __restrict__ xsh,
                 const unsigned short* __restrict__ wp,
                 const float* __restrict__ b1, const float* __restrict__ b2,
                 const float* __restrict__ b3,
                 float* __restrict__ out)
{
    // branch decode from global column-tile index
    const int gx = blockIdx.x;
    int br, nt;
    if (gx < 196)      { br = 0; nt = gx; }
    else if (gx < 391) { br = 1; nt = gx - 196; }
    else               { br = 2; nt = gx - 391; }
    const int Kp   = (br == 0) ? 928 : (br == 1) ? 1216 : 1504;
    const int Nw   = 391 - br;
    const int NTOT = Nw * 64;
    const unsigned short* Wp = wp + ((br == 0) ? 0 : (br == 1) ? 256 * 928 : 256 * (928 + 1216));
    const float* bg = (br == 0) ? b1 : (br == 1) ? b2 : b3;
    const int mt    = blockIdx.y;
    const int dbase = mt * 128;
    const int n0    = nt * 128;
    const int nch   = Kp >> 5;

    __shared__ unsigned short Wl[2][128][32];
    __shared__ unsigned short Xl[2][128][32];

    const int tid  = threadIdx.x;
    const int lane = tid & 63;
    const int wid  = tid >> 6;
    const int rsub = lane >> 2;          // staging row within 16-row group
    const int g8   = (lane & 3) * 8;     // staging col element offset
    const int wr = wid >> 1, wc = wid & 1;
    const int lr = lane & 15, lg = lane >> 4;
    const int lg8 = lg * 8;

    // per-thread global staging addresses (advance by 32 elems per chunk)
    const unsigned short* gA[2];
    const unsigned short* gX[2];
#pragma unroll
    for (int j = 0; j < 2; ++j) {
        int rowA = j * 64 + wid * 16 + rsub;
        gA[j] = Wp + (long)(dbase + rowA) * Kp + g8;
        int nX = n0 + j * 64 + wid * 16 + rsub;
        if (nX < NTOT) {
            int b = nX / Nw;
            int i = nX - b * Nw;
            int m = b * SEQ + i;                 // flat row in x
            const unsigned short* base = (m & 1) ? xsh : xp;
            long eoff = (long)m * EMB - ((m & 1) ? 4 : 0) + g8;
            gX[j] = base + eoff;
        } else {
            gX[j] = xp + g8;                     // harmless garbage; masked later
        }
    }

    f32x4 acc[4][4];
#pragma unroll
    for (int i = 0; i < 4; ++i)
#pragma unroll
        for (int j = 0; j < 4; ++j)
            acc[i][j] = (f32x4)0.0f;

    // prologue: stage chunk 0 into buf 0
#pragma unroll
    for (int j = 0; j < 2; ++j) {
        gload_lds16(gA[j], &Wl[0][j * 64 + wid * 16][0]);
        gload_lds16(gX[j], &Xl[0][j * 64 + wid * 16][0]);
    }
    __syncthreads();

    for (int c = 0; c < nch; ++c) {
        const int cur = c & 1;
        if (c + 1 < nch) {
            const int k0 = (c + 1) << 5;
#pragma unroll
            for (int j = 0; j < 2; ++j) {
                gload_lds16(gA[j] + k0, &Wl[cur ^ 1][j * 64 + wid * 16][0]);
                gload_lds16(gX[j] + k0, &Xl[cur ^ 1][j * 64 + wid * 16][0]);
            }
        }
        short8 af[4], bx[4];
#pragma unroll
        for (int mi = 0; mi < 4; ++mi)
            af[mi] = *(const short8*)&Wl[cur][wr * 64 + mi * 16 + lr][lg8];
#pragma unroll
        for (int ni = 0; ni < 4; ++ni)
            bx[ni] = *(const short8*)&Xl[cur][wc * 64 + ni * 16 + lr][lg8];
#pragma unroll
        for (int mi = 0; mi < 4; ++mi)
#pragma unroll
            for (int ni = 0; ni < 4; ++ni)
                acc[mi][ni] = __builtin_amdgcn_mfma_f32_16x16x32_bf16(af[mi], bx[ni], acc[mi][ni], 0, 0, 0);
        __syncthreads();
    }

    // epilogue: bias+relu+mask, segmented (<=2 batches per 64-window span)
    const int obr = br * 256;
    const int nb  = n0 + wc * 64;                    // wave's first window (global)
    const int B0  = nb / Nw;                         // wave-uniform
    const bool cross = (nb + 63) >= (B0 + 1) * Nw;
#pragma unroll
    for (int mi = 0; mi < 4; ++mi) {
#pragma unroll
        for (int r = 0; r < 4; ++r) {
            const int d = dbase + wr * 64 + mi * 16 + lg * 4 + r;
            const float bv = bg[d];
            float vlo = 0.f, vhi = 0.f;
#pragma unroll
            for (int ni = 0; ni < 4; ++ni) {
                int n = nb + ni * 16 + lr;
                float v = fmaxf(acc[mi][ni][r] + bv, 0.f);
                if (n >= NTOT) v = 0.f;
                bool hi = (n - B0 * Nw) >= Nw;
                vlo = hi ? vlo : fmaxf(vlo, v);
                vhi = hi ? fmaxf(vhi, v) : vhi;
            }
#pragma unroll
            for (int off = 1; off < 16; off <<= 1) {
                vlo = fmaxf(vlo, __shfl_xor(vlo, off));
                vhi = fmaxf(vhi, __shfl_xor(vhi, off));
            }
            if (lr == 0 && B0 < 64)
                atomicMax((int*)(out + (long)B0 * 768 + obr + d), __float_as_int(vlo));
            if (lr == 0 && cross && (B0 + 1) < 64)
                atomicMax((int*)(out + (long)(B0 + 1) * 768 + obr + d), __float_as_int(vhi));
        }
    }
}

// ---------------- fallback (R1 kernel) if ws too small ----------------

__device__ __forceinline__ void load_chunk(const float* __restrict__ Wg,
                                           const float* __restrict__ xb,
                                           int K, int dbase, int i0, int k0, int tid,
                                           float4 wv[4], float4 xv[4])
{
#pragma unroll
    for (int i = 0; i < 4; ++i) {
        int fi  = tid + (i << 8);
        int row = fi >> 3;
        int c4  = (fi & 7) << 2;
        int col = k0 + c4;
        if (col < K)
            wv[i] = *(const float4*)(Wg + (long)(dbase + row) * K + col);
        else
            wv[i] = make_float4(0.f, 0.f, 0.f, 0.f);
        int off = (i0 + row) * EMB + col;
        int lim = SEQ * EMB - 4;
        if (off > lim) off = lim;
        xv[i] = *(const float4*)(xb + off);
    }
}

__device__ __forceinline__ void write_chunk(unsigned short (*Wb)[40],
                                            unsigned short (*Xb)[40],
                                            int tid, const float4 wv[4], const float4 xv[4])
{
#pragma unroll
    for (int i = 0; i < 4; ++i) {
        int fi  = tid + (i << 8);
        int row = fi >> 3;
        int c4  = (fi & 7) << 2;
        *(ushort4*)&Wb[row][c4] = make_ushort4(f2b(wv[i].x), f2b(wv[i].y), f2b(wv[i].z), f2b(wv[i].w));
        *(ushort4*)&Xb[row][c4] = make_ushort4(f2b(xv[i].x), f2b(xv[i].y), f2b(xv[i].z), f2b(xv[i].w));
    }
}

__global__ __launch_bounds__(256, 2)
void convmax_fallback(const float* __restrict__ x,
                      const float* __restrict__ W1, const float* __restrict__ W2,
                      const float* __restrict__ W3,
                      const float* __restrict__ b1, const float* __restrict__ b2,
                      const float* __restrict__ b3,
                      float* __restrict__ out)
{
    const int br = blockIdx.z;
    const int K  = (br == 0) ? 900 : (br == 1) ? 1200 : 1500;
    const int Nw = SEQ - 3 - br;
    const float* Wg = (br == 0) ? W1 : (br == 1) ? W2 : W3;
    const float* bg = (br == 0) ? b1 : (br == 1) ? b2 : b3;
    const int b  = blockIdx.x;
    const int mt = blockIdx.y >> 2;
    const int nt = blockIdx.y & 3;
    const int dbase = mt * 128;
    const int i0    = nt * 128;
    const float* xb = x + b * (SEQ * EMB);
    const int nch = (K + 31) >> 5;

    __shared__ unsigned short Wl[2][128][40];
    __shared__ unsigned short Xl[2][128][40];

    const int tid  = threadIdx.x;
    const int lane = tid & 63;
    const int wid  = tid >> 6;
    const int wr = wid >> 1, wc = wid & 1;
    const int lr = lane & 15, lg = lane >> 4;

    f32x4 acc[4][4];
#pragma unroll
    for (int i = 0; i < 4; ++i)
#pragma unroll
        for (int j = 0; j < 4; ++j)
            acc[i][j] = (f32x4)0.0f;

    {
        float4 wv[4], xv[4];
        load_chunk(Wg, xb, K, dbase, i0, 0, tid, wv, xv);
        write_chunk(Wl[0], Xl[0], tid, wv, xv);
    }
    __syncthreads();

    for (int c = 0; c < nch; ++c) {
        const int cur = c & 1;
        float4 wv[4], xv[4];
        const bool pf = (c + 1 < nch);
        if (pf) load_chunk(Wg, xb, K, dbase, i0, (c + 1) << 5, tid, wv, xv);

        short8 af[4], bfr[4];
#pragma unroll
        for (int mi = 0; mi < 4; ++mi)
            af[mi] = *(const short8*)&Wl[cur][wr * 64 + mi * 16 + lr][lg * 8];
#pragma unroll
        for (int ni = 0; ni < 4; ++ni)
            bfr[ni] = *(const short8*)&Xl[cur][wc * 64 + ni * 16 + lr][lg * 8];
#pragma unroll
        for (int mi = 0; mi < 4; ++mi)
#pragma unroll
            for (int ni = 0; ni < 4; ++ni)
                acc[mi][ni] = __builtin_amdgcn_mfma_f32_16x16x32_bf16(af[mi], bfr[ni], acc[mi][ni], 0, 0, 0);

        if (pf) write_chunk(Wl[cur ^ 1], Xl[cur ^ 1], tid, wv, xv);
        __syncthreads();
    }

    const int ob = b * 768 + br * 256;
#pragma unroll
    for (int mi = 0; mi < 4; ++mi) {
#pragma unroll
        for (int r = 0; r < 4; ++r) {
            const int d = dbase + wr * 64 + mi * 16 + lg * 4 + r;
            const float bv = bg[d];
            float m = 0.f;
#pragma unroll
            for (int ni = 0; ni < 4; ++ni) {
                int win = i0 + wc * 64 + ni * 16 + lr;
                float v = acc[mi][ni][r] + bv;
                v = fmaxf(v, 0.f);
                if (win >= Nw) v = 0.f;
                m = fmaxf(m, v);
            }
#pragma unroll
            for (int off = 1; off < 16; off <<= 1)
                m = fmaxf(m, __shfl_xor(m, off));
            if (lr == 0)
                atomicMax((int*)(out + ob + d), __float_as_int(m));
        }
    }
}

// ---------------- launch ----------------

extern "C" void kernel_launch(void* const* d_in, const int* in_sizes, int n_in,
                              void* d_out, int out_size, void* d_ws, size_t ws_size,
                              hipStream_t stream) {
    const float* x  = (const float*)d_in[0];
    const float* W1 = (const float*)d_in[1];
    const float* W2 = (const float*)d_in[2];
    const float* W3 = (const float*)d_in[3];
    const float* b1 = (const float*)d_in[4];
    const float* b2 = (const float*)d_in[5];
    const float* b3 = (const float*)d_in[6];
    float* out = (float*)d_out;

    hipMemsetAsync(d_out, 0, (size_t)out_size * sizeof(float), stream);

    const long XTOT = (long)64 * SEQ * EMB;                  // 7,564,800 elements
    const size_t need = (size_t)(2 * XTOT + 256L * (928 + 1216 + 1504)) * 2;  // ~32.1 MB

    if (ws_size >= need) {
        unsigned short* xp  = (unsigned short*)d_ws;
        unsigned short* xsh = xp + XTOT;
        unsigned short* wp  = xsh + XTOT;

        int nblk_x = (int)((XTOT / 4 + 255) / 256);          // 7388
        pack_x_kernel<<<nblk_x, 256, 0, stream>>>(x, xp, xsh);
        pack_w_kernel<<<dim3(376, 1, 3), 256, 0, stream>>>(W1, W2, W3, wp);
        gemm_kernel<<<dim3(586, 2, 1), 256, 0, stream>>>(xp, xsh, wp, b1, b2, b3, out);
    } else {
        dim3 grid(64, 8, 3);
        convmax_fallback<<<grid, 256, 0, stream>>>(x, W1, W2, W3, b1, b2, b3, out);
    }
}